// Round 12
// baseline (2194.020 us; speedup 1.0000x reference)
//
#include <hip/hip_runtime.h>

typedef unsigned short ushort_t;
typedef unsigned int uint_t;

using f16x8 = __attribute__((ext_vector_type(8))) _Float16;
using f32x4 = __attribute__((ext_vector_type(4))) float;
using u32x4 = __attribute__((ext_vector_type(4))) unsigned int;

#define BATCH 64
#define SEQT 512
#define DIN 256
#define HID 256
#define G4 1024   // 4*HID
#define CH 64     // pipeline chunk (timesteps)
#define HB 32     // producer LDS h-ring depth (dump granularity)

static __device__ __forceinline__ ushort_t f16b(float x) {
    return __builtin_bit_cast(ushort_t, (_Float16)x);
}
static __device__ __forceinline__ uint_t pk2(float a, float b) {
    return (uint_t)f16b(a) | ((uint_t)f16b(b) << 16);
}
static __device__ __forceinline__ float sig_(float x) {
    return 1.f / (1.f + __expf(-x));
}
static __device__ __forceinline__ float tanh_(float x) {
    float e = __expf(2.f * x);
    return (e - 1.f) / (e + 1.f);
}

#define PINA(x) asm volatile("" : "+a"(x))
#define PINV(x) asm volatile("" : "+v"(x))

static __device__ __forceinline__ f16x8 asf16(u32x4 v) {
    return __builtin_bit_cast(f16x8, v);
}

// ---------------- prep kernels ----------------

__global__ void cvt_x_kernel(const float* __restrict__ in, ushort_t* __restrict__ out, int n4) {
    int i = blockIdx.x * blockDim.x + threadIdx.x;
    if (i < n4) {
        float4 v = ((const float4*)in)[i];
        ushort4 o;
        o.x = f16b(v.x); o.y = f16b(v.y); o.z = f16b(v.z); o.w = f16b(v.w);
        ((ushort4*)out)[i] = o;
    }
}

// W [256][1024] f32 -> Wt [1024][256] f16 bits (transpose)
__global__ void prep_wt_kernel(const float* __restrict__ W, ushort_t* __restrict__ Wt) {
    int tid = blockIdx.x * blockDim.x + threadIdx.x;
    int k = tid >> 10;
    int n = tid & 1023;
    Wt[n * DIN + k] = f16b(W[tid]);
}

// U [256][1024] f32 -> Upk [32][1024] uint4 (f16 pairs, k=8j..8j+7)
__global__ void prep_upk_kernel(const float* __restrict__ U, uint4* __restrict__ Upk) {
    int tid = blockIdx.x * blockDim.x + threadIdx.x;
    int j = tid >> 10;
    int g = tid & 1023;
    uint4 o;
    uint_t* op = &o.x;
#pragma unroll
    for (int q = 0; q < 4; ++q) {
        float a = U[(8 * j + 2 * q) * G4 + g];
        float b = U[(8 * j + 2 * q + 1) * G4 + g];
        op[q] = pk2(a, b);
    }
    Upk[tid] = o;
}

// ---------------- GEMM (layer-1 input projection; unchanged, passing) ----------------

#define GSTRIDE 40

__global__ __launch_bounds__(256) void gemm_f16_kernel(
    const ushort_t* __restrict__ A,
    const ushort_t* __restrict__ Bt,
    const float* __restrict__ bias,
    float* __restrict__ C,
    int M)
{
    const int K = DIN, N = G4;
    __shared__ ushort_t As[128 * GSTRIDE];
    __shared__ ushort_t Bs[128 * GSTRIDE];
    int tid = threadIdx.x;
    int bx = blockIdx.x & 7;
    int by = blockIdx.x >> 3;
    int m0 = by * 128, n0 = bx * 128;
    int w = tid >> 6, lane = tid & 63;
    int wr = (w >> 1) * 64, wc = (w & 1) * 64;
    int r = lane & 15, kg = lane >> 4;

    f32x4 acc[4][4];
#pragma unroll
    for (int i = 0; i < 4; ++i)
#pragma unroll
        for (int j = 0; j < 4; ++j)
            acc[i][j] = f32x4{0.f, 0.f, 0.f, 0.f};

    for (int kt = 0; kt < K; kt += 32) {
        __syncthreads();
#pragma unroll
        for (int s = 0; s < 2; ++s) {
            int chunk = tid + s * 256;
            int row = chunk >> 2;
            int ko = (chunk & 3) * 8;
            uint4 va = *(const uint4*)(A + (size_t)(m0 + row) * K + kt + ko);
            *(uint4*)(&As[row * GSTRIDE + ko]) = va;
            uint4 vb = *(const uint4*)(Bt + (size_t)(n0 + row) * K + kt + ko);
            *(uint4*)(&Bs[row * GSTRIDE + ko]) = vb;
        }
        __syncthreads();
        f16x8 af[4], bf[4];
#pragma unroll
        for (int i = 0; i < 4; ++i) {
            af[i] = *(const f16x8*)(&As[(wr + i * 16 + r) * GSTRIDE + kg * 8]);
            bf[i] = *(const f16x8*)(&Bs[(wc + i * 16 + r) * GSTRIDE + kg * 8]);
        }
#pragma unroll
        for (int i = 0; i < 4; ++i)
#pragma unroll
            for (int j = 0; j < 4; ++j)
                acc[i][j] = __builtin_amdgcn_mfma_f32_16x16x32_f16(af[i], bf[j], acc[i][j], 0, 0, 0);
    }

#pragma unroll
    for (int i = 0; i < 4; ++i)
#pragma unroll
        for (int j = 0; j < 4; ++j) {
            int col = n0 + wc + j * 16 + r;
            float bv = bias[col];
#pragma unroll
            for (int v = 0; v < 4; ++v) {
                int rowg = m0 + wr + i * 16 + kg * 4 + v;
                C[(size_t)rowg * N + col] = acc[i][j][v] + bv;
            }
        }
}

// ---------------- fused chunk-pipelined 2-layer recurrence (v2) ----------------
// vs r11: producer buffers h1 in a 16 KB LDS ring and dumps via coalesced
// agent atomics every 32 steps (no per-step global stores -> no per-step
// LLC drain at the barrier). Flag counts 32-step halves. Consumer identical
// to r11 (proven): waits flag >= 2(ch+1), atomic-stages y1, mini-GEMM, steps.

__global__ __launch_bounds__(256)
__attribute__((amdgpu_waves_per_eu(1, 1)))
void lstm_fused_kernel(
    const float* __restrict__ xz1,     // [B*T][1024] layer-1 xz (bias incl)
    const u32x4* __restrict__ Upk0,    // [32][1024]
    const u32x4* __restrict__ Upk1,    // [32][1024]
    const ushort_t* __restrict__ Wt1,  // [1024][256] f16
    const float* __restrict__ b1,      // [1024]
    uint_t* y1pk,                      // [B*T][128] packed h1 (u32 = 2 f16)
    int* flags,                        // [B][32] (128-B stride)
    float* xz2ws,                      // [B][CH][1024] f32 scratch
    float* out,                        // [B*T][256]
    int T)
{
    __shared__ __align__(16) u32x4 Uld[4][2][16][64];   // 128 KB
    __shared__ __align__(16) ushort_t ys[32][264];      // 16.5 KB (consumer A-stage / producer h-ring)
    __shared__ __align__(16) ushort_t h16[2][HID];      // 1 KB

    const int tid = threadIdx.x;
    const int w = tid >> 6;          // wave 0..3
    const int l = tid & 63;
    const int lg = l >> 4;           // lane group 0..3
    const int lr = l & 15;
    const int role = (int)(blockIdx.x >> 6);
    const int b = (int)(blockIdx.x & 63);

    const int hcol = w * 64 + lg * 16 + lr;
    const u32x4* Upk = role ? Upk1 : Upk0;
    int* flagp = flags + b * 32;

    // ---- preload U fragments (r7 layout: fi = gb*4+ti, ti=0..3) ----
    u32x4 ua[64];   // kt0-3 -> AGPR
    u32x4 uv[32];   // kt4-5 -> VGPR
#pragma unroll
    for (int gb = 0; gb < 4; ++gb)
#pragma unroll
        for (int ti = 0; ti < 4; ++ti) {
            int col = (gb * 16 + w * 4 + ti) * 16 + lr;
            int fi = gb * 4 + ti;
#pragma unroll
            for (int kt = 0; kt < 4; ++kt)
                ua[fi * 4 + kt] = Upk[(kt * 4 + lg) * 1024 + col];
#pragma unroll
            for (int k2 = 0; k2 < 2; ++k2)
                uv[fi * 2 + k2] = Upk[((4 + k2) * 4 + lg) * 1024 + col];
        }
#pragma unroll
    for (int i = 0; i < 64; ++i) PINA(ua[i]);
#pragma unroll
    for (int i = 0; i < 32; ++i) PINV(uv[i]);

#pragma unroll
    for (int gb = 0; gb < 4; ++gb)
#pragma unroll
        for (int ti = 0; ti < 4; ++ti) {
            int col = (gb * 16 + w * 4 + ti) * 16 + lr;
            int fi = gb * 4 + ti;
#pragma unroll
            for (int k2 = 0; k2 < 2; ++k2)
                Uld[w][k2][fi][l] = Upk[((6 + k2) * 4 + lg) * 1024 + col];
        }

    h16[0][tid] = 0;
    float c = 0.f;

    if (role == 0) {
        // ================= layer-1 producer =================
        uint_t* hr = (uint_t*)&ys[0][0];   // [HB][128] packed h ring (16 KB)
        const float* xz_b = xz1 + (size_t)b * T * G4;
        float xzc[4];
#pragma unroll
        for (int gb = 0; gb < 4; ++gb) xzc[gb] = xz_b[gb * 256 + hcol];
        __syncthreads();

        for (int t = 0; t < T; ++t) {
            const int cur = t & 1, nxt = cur ^ 1;

            f16x8 af[8];
#pragma unroll
            for (int kt = 0; kt < 8; ++kt)
                af[kt] = *(const f16x8*)((const char*)&h16[cur][0] + kt * 64 + lg * 16);

            float xzn[4];
            {
                const float* xztn = xz_b + (size_t)((t + 1 < T) ? (t + 1) : t) * G4;
#pragma unroll
                for (int gb = 0; gb < 4; ++gb) xzn[gb] = xztn[gb * 256 + hcol];
            }

            float zg[4];
#pragma unroll
            for (int gb = 0; gb < 4; ++gb) {
                f32x4 accA[4], accB[4];
#pragma unroll
                for (int ti = 0; ti < 4; ++ti) {
                    accA[ti] = f32x4{0.f, 0.f, 0.f, 0.f};
                    accB[ti] = f32x4{0.f, 0.f, 0.f, 0.f};
                }
#pragma unroll
                for (int ti = 0; ti < 4; ++ti) {
                    int fi = gb * 4 + ti;
#pragma unroll
                    for (int kt = 0; kt < 4; ++kt)
                        accA[ti] = __builtin_amdgcn_mfma_f32_16x16x32_f16(
                            af[kt], asf16(ua[fi * 4 + kt]), accA[ti], 0, 0, 0);
#pragma unroll
                    for (int k2 = 0; k2 < 2; ++k2)
                        accB[ti] = __builtin_amdgcn_mfma_f32_16x16x32_f16(
                            af[4 + k2], asf16(uv[fi * 2 + k2]), accB[ti], 0, 0, 0);
#pragma unroll
                    for (int k2 = 0; k2 < 2; ++k2) {
                        u32x4 ub = Uld[w][k2][fi][l];
                        accB[ti] = __builtin_amdgcn_mfma_f32_16x16x32_f16(
                            af[6 + k2], asf16(ub), accB[ti], 0, 0, 0);
                    }
                }
                float za = (lg == 0) ? accA[0][0] : (lg == 1) ? accA[1][0]
                         : (lg == 2) ? accA[2][0] : accA[3][0];
                float zb = (lg == 0) ? accB[0][0] : (lg == 1) ? accB[1][0]
                         : (lg == 2) ? accB[2][0] : accB[3][0];
                zg[gb] = za + zb + xzc[gb];
            }

            c = sig_(zg[1]) * c + sig_(zg[0]) * tanh_(zg[2]);
            float h = sig_(zg[3]) * tanh_(c);

            h16[nxt][hcol] = f16b(h);
            // buffer packed h in the LDS ring (no global store this step)
            {
                uint_t hb = (uint_t)f16b(h);
                uint_t pb = (uint_t)(unsigned)__shfl_xor((int)hb, 1);
                if (!(l & 1))
                    hr[(t & (HB - 1)) * 128 + (hcol >> 1)] = hb | (pb << 16);
            }
#pragma unroll
            for (int gb = 0; gb < 4; ++gb) xzc[gb] = xzn[gb];

            __syncthreads();   // publishes h16 + hr for this step (LDS only)

            if ((t & (HB - 1)) == (HB - 1)) {
                // dump ring: HB*128 = 4096 u32, 16 per thread, coalesced
                int t0 = t - (HB - 1);
#pragma unroll
                for (int it = 0; it < 16; ++it) {
                    int idx = it * 256 + tid;
                    int row = idx >> 7;
                    int j = idx & 127;
                    __hip_atomic_store(&y1pk[(size_t)(b * T + t0 + row) * 128 + j],
                                       hr[row * 128 + j],
                                       __ATOMIC_RELAXED, __HIP_MEMORY_SCOPE_AGENT);
                }
                __syncthreads();   // drain dump stores once per HB steps
                if (tid == 0)
                    __hip_atomic_store(flagp, (t + 1) / HB, __ATOMIC_RELEASE,
                                       __HIP_MEMORY_SCOPE_AGENT);
            }
        }
    } else {
        // ================= layer-2 consumer (r11-proven) =================
        float* xz2row = xz2ws + (size_t)b * (CH * G4);
        float b1w[16];
#pragma unroll
        for (int ct = 0; ct < 16; ++ct) b1w[ct] = b1[(w * 16 + ct) * 16 + lr];
        size_t obase = (size_t)b * T * HID + hcol;
        __syncthreads();

        const int NCH = T / CH;
        const int HPC = CH / HB;   // flag halves per chunk = 2
        for (int ch = 0; ch < NCH; ++ch) {
            if (tid == 0) {
                while (__hip_atomic_load(flagp, __ATOMIC_ACQUIRE, __HIP_MEMORY_SCOPE_AGENT)
                       < (ch + 1) * HPC)
                    __builtin_amdgcn_s_sleep(32);
            }
            __syncthreads();

            // ---- mini-GEMM: xz2[64][1024] = y1_chunk[64][256] @ W1t + b1 ----
#pragma unroll
            for (int half = 0; half < 2; ++half) {
                __syncthreads();
#pragma unroll
                for (int it = 0; it < 16; ++it) {
                    int idx = it * 256 + tid;
                    int row = idx >> 7;
                    int j = idx & 127;
                    uint_t v = __hip_atomic_load(
                        &y1pk[(size_t)(b * T + ch * CH + half * 32 + row) * 128 + j],
                        __ATOMIC_RELAXED, __HIP_MEMORY_SCOPE_AGENT);
                    *(uint_t*)&ys[row][2 * j] = v;
                }
                __syncthreads();
#pragma unroll
                for (int ct = 0; ct < 16; ++ct) {
                    int ctI = w * 16 + ct;
                    u32x4 bf[8];
#pragma unroll
                    for (int kt = 0; kt < 8; ++kt)
                        bf[kt] = *(const u32x4*)(Wt1 + (size_t)(ctI * 16 + lr) * DIN + kt * 32 + lg * 8);
                    f32x4 acc[2];
                    acc[0] = f32x4{0.f, 0.f, 0.f, 0.f};
                    acc[1] = f32x4{0.f, 0.f, 0.f, 0.f};
#pragma unroll
                    for (int rt = 0; rt < 2; ++rt)
#pragma unroll
                        for (int kt = 0; kt < 8; ++kt) {
                            f16x8 af = *(const f16x8*)&ys[rt * 16 + lr][kt * 32 + lg * 8];
                            acc[rt] = __builtin_amdgcn_mfma_f32_16x16x32_f16(
                                af, asf16(bf[kt]), acc[rt], 0, 0, 0);
                        }
#pragma unroll
                    for (int rt = 0; rt < 2; ++rt)
#pragma unroll
                        for (int v = 0; v < 4; ++v) {
                            int row = half * 32 + rt * 16 + lg * 4 + v;
                            xz2row[(size_t)row * G4 + ctI * 16 + lr] = acc[rt][v] + b1w[ct];
                        }
                }
            }
            __syncthreads();

            // ---- 64 recurrence steps (regs/LDS/own-XCD xz2 only) ----
            for (int tb = 0; tb < CH; ++tb) {
                const int t = ch * CH + tb;
                const int cur = t & 1, nxt = cur ^ 1;

                float xzc[4];
#pragma unroll
                for (int gb = 0; gb < 4; ++gb)
                    xzc[gb] = xz2row[(size_t)tb * G4 + gb * 256 + hcol];

                f16x8 af[8];
#pragma unroll
                for (int kt = 0; kt < 8; ++kt)
                    af[kt] = *(const f16x8*)((const char*)&h16[cur][0] + kt * 64 + lg * 16);

                float zg[4];
#pragma unroll
                for (int gb = 0; gb < 4; ++gb) {
                    f32x4 accA[4], accB[4];
#pragma unroll
                    for (int ti = 0; ti < 4; ++ti) {
                        accA[ti] = f32x4{0.f, 0.f, 0.f, 0.f};
                        accB[ti] = f32x4{0.f, 0.f, 0.f, 0.f};
                    }
#pragma unroll
                    for (int ti = 0; ti < 4; ++ti) {
                        int fi = gb * 4 + ti;
#pragma unroll
                        for (int kt = 0; kt < 4; ++kt)
                            accA[ti] = __builtin_amdgcn_mfma_f32_16x16x32_f16(
                                af[kt], asf16(ua[fi * 4 + kt]), accA[ti], 0, 0, 0);
#pragma unroll
                        for (int k2 = 0; k2 < 2; ++k2)
                            accB[ti] = __builtin_amdgcn_mfma_f32_16x16x32_f16(
                                af[4 + k2], asf16(uv[fi * 2 + k2]), accB[ti], 0, 0, 0);
#pragma unroll
                        for (int k2 = 0; k2 < 2; ++k2) {
                            u32x4 ub = Uld[w][k2][fi][l];
                            accB[ti] = __builtin_amdgcn_mfma_f32_16x16x32_f16(
                                af[6 + k2], asf16(ub), accB[ti], 0, 0, 0);
                        }
                    }
                    float za = (lg == 0) ? accA[0][0] : (lg == 1) ? accA[1][0]
                             : (lg == 2) ? accA[2][0] : accA[3][0];
                    float zb = (lg == 0) ? accB[0][0] : (lg == 1) ? accB[1][0]
                             : (lg == 2) ? accB[2][0] : accB[3][0];
                    zg[gb] = za + zb + xzc[gb];
                }

                c = sig_(zg[1]) * c + sig_(zg[0]) * tanh_(zg[2]);
                float h = sig_(zg[3]) * tanh_(c);

                h16[nxt][hcol] = f16b(h);
                out[obase] = h;
                obase += HID;

                __syncthreads();
            }
        }
    }
}

// ---------------- launch ----------------

extern "C" void kernel_launch(void* const* d_in, const int* in_sizes, int n_in,
                              void* d_out, int out_size, void* d_ws, size_t ws_size,
                              hipStream_t stream) {
    const float* x  = (const float*)d_in[0];
    const float* W0 = (const float*)d_in[1];
    const float* U0 = (const float*)d_in[2];
    const float* b0 = (const float*)d_in[3];
    const float* W1 = (const float*)d_in[4];
    const float* U1 = (const float*)d_in[5];
    const float* b1 = (const float*)d_in[6];
    float* out = (float*)d_out;

    const size_t M = (size_t)BATCH * SEQT;   // 32768

    char* ws = (char*)d_ws;
    ushort_t* xf16  = (ushort_t*)(ws);                         // 16 MB @ 0 (dead after GEMM1)
    float*    xz2ws = (float*)   (ws);                         // aliases xf16 (16 MB)
    uint_t*   y1pk  = (uint_t*)  (ws + (16u << 20));           // 16 MB @ 16M
    ushort_t* Wt0   = (ushort_t*)(ws + (32u << 20));           // 0.5 MB @ 32M
    ushort_t* Wt1   = (ushort_t*)(ws + (32u << 20) + 524288);  // 0.5 MB @ 32.5M
    u32x4*    Upk0  = (u32x4*)   (ws + (33u << 20));           // 0.5 MB @ 33M
    u32x4*    Upk1  = (u32x4*)   (ws + (33u << 20) + 524288);  // 0.5 MB @ 33.5M
    int*      flags = (int*)     (ws + (34u << 20));           // 8 KB @ 34M
    float*    xz1   = (float*)   (ws + (35u << 20));           // 128 MB @ 35M

    // reset handoff flags every launch (graph-replay safe)
    hipMemsetAsync(flags, 0, BATCH * 32 * sizeof(int), stream);

    {
        int n4 = (int)(M * DIN / 4);
        cvt_x_kernel<<<dim3((n4 + 255) / 256), dim3(256), 0, stream>>>(x, xf16, n4);
        prep_wt_kernel<<<dim3(1024), dim3(256), 0, stream>>>(W0, Wt0);
        prep_wt_kernel<<<dim3(1024), dim3(256), 0, stream>>>(W1, Wt1);
        prep_upk_kernel<<<dim3(128), dim3(256), 0, stream>>>(U0, (uint4*)Upk0);
        prep_upk_kernel<<<dim3(128), dim3(256), 0, stream>>>(U1, (uint4*)Upk1);
    }

    // layer-1 input projection
    gemm_f16_kernel<<<dim3((int)(M / 128) * 8), dim3(256), 0, stream>>>(xf16, Wt0, b0, xz1, (int)M);

    // fused chunk-pipelined 2-layer recurrence (layer-2 projection folded in)
    lstm_fused_kernel<<<dim3(128), dim3(256), 0, stream>>>(
        xz1, Upk0, Upk1, Wt1, b1, y1pk, flags, xz2ws, out, SEQT);
}

// Round 13
// 1190.722 us; speedup vs baseline: 1.8426x; 1.8426x over previous
//
#include <hip/hip_runtime.h>

typedef unsigned short ushort_t;
typedef unsigned int uint_t;

using f16x8 = __attribute__((ext_vector_type(8))) _Float16;
using f32x4 = __attribute__((ext_vector_type(4))) float;
using u32x4 = __attribute__((ext_vector_type(4))) unsigned int;

#define BATCH 64
#define SEQT 512
#define DIN 256
#define HID 256
#define G4 1024   // 4*HID
#define CH 32     // pipeline chunk (timesteps) == producer ring depth
#define NCH (SEQT / CH)

static __device__ __forceinline__ ushort_t f16b(float x) {
    return __builtin_bit_cast(ushort_t, (_Float16)x);
}
static __device__ __forceinline__ float f16f(ushort_t u) {
    return (float)__builtin_bit_cast(_Float16, u);
}
static __device__ __forceinline__ uint_t pk2(float a, float b) {
    return (uint_t)f16b(a) | ((uint_t)f16b(b) << 16);
}
static __device__ __forceinline__ float sig_(float x) {
    return 1.f / (1.f + __expf(-x));
}
static __device__ __forceinline__ float tanh_(float x) {
    float e = __expf(2.f * x);
    return (e - 1.f) / (e + 1.f);
}

#define PINA(x) asm volatile("" : "+a"(x))
#define PINV(x) asm volatile("" : "+v"(x))

static __device__ __forceinline__ f16x8 asf16(u32x4 v) {
    return __builtin_bit_cast(f16x8, v);
}

// ---------------- prep kernels ----------------

__global__ void cvt_x_kernel(const float* __restrict__ in, ushort_t* __restrict__ out, int n4) {
    int i = blockIdx.x * blockDim.x + threadIdx.x;
    if (i < n4) {
        float4 v = ((const float4*)in)[i];
        ushort4 o;
        o.x = f16b(v.x); o.y = f16b(v.y); o.z = f16b(v.z); o.w = f16b(v.w);
        ((ushort4*)out)[i] = o;
    }
}

// W [256][1024] f32 -> Wt [1024][256] f16 bits (transpose)
__global__ void prep_wt_kernel(const float* __restrict__ W, ushort_t* __restrict__ Wt) {
    int tid = blockIdx.x * blockDim.x + threadIdx.x;
    int k = tid >> 10;
    int n = tid & 1023;
    Wt[n * DIN + k] = f16b(W[tid]);
}

// U [256][1024] f32 -> Upk [32][1024] uint4 (f16 pairs, k=8j..8j+7)
__global__ void prep_upk_kernel(const float* __restrict__ U, uint4* __restrict__ Upk) {
    int tid = blockIdx.x * blockDim.x + threadIdx.x;
    int j = tid >> 10;
    int g = tid & 1023;
    uint4 o;
    uint_t* op = &o.x;
#pragma unroll
    for (int q = 0; q < 4; ++q) {
        float a = U[(8 * j + 2 * q) * G4 + g];
        float b = U[(8 * j + 2 * q + 1) * G4 + g];
        op[q] = pk2(a, b);
    }
    Upk[tid] = o;
}

// ---------------- GEMM1 (layer-1 input projection; f16 output) ----------------

#define GSTRIDE 40

__global__ __launch_bounds__(256) void gemm_f16_kernel(
    const ushort_t* __restrict__ A,
    const ushort_t* __restrict__ Bt,
    const float* __restrict__ bias,
    ushort_t* __restrict__ C,         // f16 output
    int M)
{
    const int K = DIN, N = G4;
    __shared__ ushort_t As[128 * GSTRIDE];
    __shared__ ushort_t Bs[128 * GSTRIDE];
    int tid = threadIdx.x;
    int bx = blockIdx.x & 7;
    int by = blockIdx.x >> 3;
    int m0 = by * 128, n0 = bx * 128;
    int w = tid >> 6, lane = tid & 63;
    int wr = (w >> 1) * 64, wc = (w & 1) * 64;
    int r = lane & 15, kg = lane >> 4;

    f32x4 acc[4][4];
#pragma unroll
    for (int i = 0; i < 4; ++i)
#pragma unroll
        for (int j = 0; j < 4; ++j)
            acc[i][j] = f32x4{0.f, 0.f, 0.f, 0.f};

    for (int kt = 0; kt < K; kt += 32) {
        __syncthreads();
#pragma unroll
        for (int s = 0; s < 2; ++s) {
            int chunk = tid + s * 256;
            int row = chunk >> 2;
            int ko = (chunk & 3) * 8;
            uint4 va = *(const uint4*)(A + (size_t)(m0 + row) * K + kt + ko);
            *(uint4*)(&As[row * GSTRIDE + ko]) = va;
            uint4 vb = *(const uint4*)(Bt + (size_t)(n0 + row) * K + kt + ko);
            *(uint4*)(&Bs[row * GSTRIDE + ko]) = vb;
        }
        __syncthreads();
        f16x8 af[4], bf[4];
#pragma unroll
        for (int i = 0; i < 4; ++i) {
            af[i] = *(const f16x8*)(&As[(wr + i * 16 + r) * GSTRIDE + kg * 8]);
            bf[i] = *(const f16x8*)(&Bs[(wc + i * 16 + r) * GSTRIDE + kg * 8]);
        }
#pragma unroll
        for (int i = 0; i < 4; ++i)
#pragma unroll
            for (int j = 0; j < 4; ++j)
                acc[i][j] = __builtin_amdgcn_mfma_f32_16x16x32_f16(af[i], bf[j], acc[i][j], 0, 0, 0);
    }

#pragma unroll
    for (int i = 0; i < 4; ++i)
#pragma unroll
        for (int j = 0; j < 4; ++j) {
            int col = n0 + wc + j * 16 + r;
            float bv = bias[col];
#pragma unroll
            for (int v = 0; v < 4; ++v) {
                int rowg = m0 + wr + i * 16 + kg * 4 + v;
                C[(size_t)rowg * N + col] = f16b(acc[i][j][v] + bv);
            }
        }
}

// ---------------- 3-stage pipelined 2-layer recurrence ----------------
// 192 WGs x 256 thr. Blocks 0-63: layer-1 producer (r7 body, f16 xz1,
// LDS ring -> y1pk agent atomics + flag1 per CH=32 steps).
// Blocks 64-127: GEMM stage: per chunk stage y1pk -> LDS, mini-GEMM
// xz2 = y1@W1t + b1, agent-atomic-store into 4-deep xz2 ring, flag2.
// Blocks 128-191: layer-2 pure stepper: per chunk one acquire, then 32
// r7-steps reading xz2 via relaxed agent atomics (hidden under MFMAs).
// Backpressure: GEMM waits consumer flag3 >= ch-3 (ring never overruns).

__global__ __launch_bounds__(256)
__attribute__((amdgpu_waves_per_eu(1, 1)))
void lstm_pipe3_kernel(
    const ushort_t* __restrict__ xz1h,  // [B*T][1024] f16 (bias incl)
    const u32x4* __restrict__ Upk0,     // [32][1024]
    const u32x4* __restrict__ Upk1,     // [32][1024]
    const ushort_t* __restrict__ Wt1,   // [1024][256] f16
    const float* __restrict__ b1,       // [1024]
    uint_t* y1pk,                       // [B*T][128] packed h1
    int* flag1, int* flag2, int* flag3, // [B][32] each (128-B stride)
    uint_t* xz2u,                       // [B][4][CH][1024] f32-bits ring
    float* __restrict__ out,            // [B*T][256]
    int T)
{
    __shared__ __align__(16) u32x4 Uld[4][2][16][64];   // 128 KB
    __shared__ __align__(16) ushort_t ys[32][264];      // 16.5 KB (gemm A-stage / producer ring)
    __shared__ __align__(16) ushort_t h16[2][HID];      // 1 KB

    const int tid = threadIdx.x;
    const int w = tid >> 6;
    const int l = tid & 63;
    const int lg = l >> 4;
    const int lr = l & 15;
    const int role = (int)(blockIdx.x >> 6);   // 0 producer, 1 gemm, 2 consumer
    const int b = (int)(blockIdx.x & 63);
    const int hcol = w * 64 + lg * 16 + lr;

    int* f1p = flag1 + b * 32;
    int* f2p = flag2 + b * 32;
    int* f3p = flag3 + b * 32;

    if (role == 1) {
        // ================= GEMM stage =================
        float b1w[16];
#pragma unroll
        for (int ct = 0; ct < 16; ++ct) b1w[ct] = b1[(w * 16 + ct) * 16 + lr];
        __syncthreads();

        for (int ch = 0; ch < NCH; ++ch) {
            if (tid == 0) {
                while (__hip_atomic_load(f1p, __ATOMIC_ACQUIRE, __HIP_MEMORY_SCOPE_AGENT) < ch + 1)
                    __builtin_amdgcn_s_sleep(32);
                while (__hip_atomic_load(f3p, __ATOMIC_ACQUIRE, __HIP_MEMORY_SCOPE_AGENT) < ch - 3)
                    __builtin_amdgcn_s_sleep(32);
            }
            __syncthreads();

            // stage chunk: 32 rows x 128 u32
#pragma unroll
            for (int it = 0; it < 16; ++it) {
                int idx = it * 256 + tid;
                int row = idx >> 7;
                int j = idx & 127;
                uint_t v = __hip_atomic_load(
                    &y1pk[(size_t)(b * T + ch * CH + row) * 128 + j],
                    __ATOMIC_RELAXED, __HIP_MEMORY_SCOPE_AGENT);
                *(uint_t*)&ys[row][2 * j] = v;
            }
            __syncthreads();

            uint_t* xzbuf = xz2u + ((size_t)(b * 4 + (ch & 3)) * CH) * G4;
#pragma unroll
            for (int ct = 0; ct < 16; ++ct) {
                int ctI = w * 16 + ct;
                u32x4 bf[8];
#pragma unroll
                for (int kt = 0; kt < 8; ++kt)
                    bf[kt] = *(const u32x4*)(Wt1 + (size_t)(ctI * 16 + lr) * DIN + kt * 32 + lg * 8);
                f32x4 acc[2];
                acc[0] = f32x4{0.f, 0.f, 0.f, 0.f};
                acc[1] = f32x4{0.f, 0.f, 0.f, 0.f};
#pragma unroll
                for (int rt = 0; rt < 2; ++rt)
#pragma unroll
                    for (int kt = 0; kt < 8; ++kt) {
                        f16x8 af = *(const f16x8*)&ys[rt * 16 + lr][kt * 32 + lg * 8];
                        acc[rt] = __builtin_amdgcn_mfma_f32_16x16x32_f16(
                            af, asf16(bf[kt]), acc[rt], 0, 0, 0);
                    }
                // C: row=(lane>>4)*4+v, col=lane&15 (verified layout)
#pragma unroll
                for (int rt = 0; rt < 2; ++rt)
#pragma unroll
                    for (int v = 0; v < 4; ++v) {
                        int row = rt * 16 + lg * 4 + v;
                        float z = acc[rt][v] + b1w[ct];
                        __hip_atomic_store(&xzbuf[(size_t)row * G4 + ctI * 16 + lr],
                                           __builtin_bit_cast(uint_t, z),
                                           __ATOMIC_RELAXED, __HIP_MEMORY_SCOPE_AGENT);
                    }
            }
            __syncthreads();   // drain stores before flag
            if (tid == 0)
                __hip_atomic_store(f2p, ch + 1, __ATOMIC_RELEASE, __HIP_MEMORY_SCOPE_AGENT);
        }
        return;
    }

    // ---- roles 0,2: preload U fragments (r7 layout) ----
    const u32x4* Upk = (role == 2) ? Upk1 : Upk0;
    u32x4 ua[64];   // kt0-3 -> AGPR
    u32x4 uv[32];   // kt4-5 -> VGPR
#pragma unroll
    for (int gb = 0; gb < 4; ++gb)
#pragma unroll
        for (int ti = 0; ti < 4; ++ti) {
            int col = (gb * 16 + w * 4 + ti) * 16 + lr;
            int fi = gb * 4 + ti;
#pragma unroll
            for (int kt = 0; kt < 4; ++kt)
                ua[fi * 4 + kt] = Upk[(kt * 4 + lg) * 1024 + col];
#pragma unroll
            for (int k2 = 0; k2 < 2; ++k2)
                uv[fi * 2 + k2] = Upk[((4 + k2) * 4 + lg) * 1024 + col];
        }
#pragma unroll
    for (int i = 0; i < 64; ++i) PINA(ua[i]);
#pragma unroll
    for (int i = 0; i < 32; ++i) PINV(uv[i]);

#pragma unroll
    for (int gb = 0; gb < 4; ++gb)
#pragma unroll
        for (int ti = 0; ti < 4; ++ti) {
            int col = (gb * 16 + w * 4 + ti) * 16 + lr;
            int fi = gb * 4 + ti;
#pragma unroll
            for (int k2 = 0; k2 < 2; ++k2)
                Uld[w][k2][fi][l] = Upk[((6 + k2) * 4 + lg) * 1024 + col];
        }

    h16[0][tid] = 0;
    float c = 0.f;

#define STEP_BODY(AF, XZC, ZG)                                                        \
    {                                                                                 \
        _Pragma("unroll")                                                             \
        for (int gb = 0; gb < 4; ++gb) {                                              \
            f32x4 accA[4], accB[4];                                                   \
            _Pragma("unroll")                                                         \
            for (int ti = 0; ti < 4; ++ti) {                                          \
                accA[ti] = f32x4{0.f, 0.f, 0.f, 0.f};                                 \
                accB[ti] = f32x4{0.f, 0.f, 0.f, 0.f};                                 \
            }                                                                         \
            _Pragma("unroll")                                                         \
            for (int ti = 0; ti < 4; ++ti) {                                          \
                int fi = gb * 4 + ti;                                                 \
                _Pragma("unroll")                                                     \
                for (int kt = 0; kt < 4; ++kt)                                        \
                    accA[ti] = __builtin_amdgcn_mfma_f32_16x16x32_f16(                \
                        AF[kt], asf16(ua[fi * 4 + kt]), accA[ti], 0, 0, 0);           \
                _Pragma("unroll")                                                     \
                for (int k2 = 0; k2 < 2; ++k2)                                        \
                    accB[ti] = __builtin_amdgcn_mfma_f32_16x16x32_f16(                \
                        AF[4 + k2], asf16(uv[fi * 2 + k2]), accB[ti], 0, 0, 0);       \
                _Pragma("unroll")                                                     \
                for (int k2 = 0; k2 < 2; ++k2) {                                      \
                    u32x4 ub = Uld[w][k2][fi][l];                                     \
                    accB[ti] = __builtin_amdgcn_mfma_f32_16x16x32_f16(                \
                        AF[6 + k2], asf16(ub), accB[ti], 0, 0, 0);                    \
                }                                                                     \
            }                                                                         \
            float za = (lg == 0) ? accA[0][0] : (lg == 1) ? accA[1][0]                \
                     : (lg == 2) ? accA[2][0] : accA[3][0];                           \
            float zb = (lg == 0) ? accB[0][0] : (lg == 1) ? accB[1][0]                \
                     : (lg == 2) ? accB[2][0] : accB[3][0];                           \
            ZG[gb] = za + zb + XZC[gb];                                               \
        }                                                                             \
    }

    if (role == 0) {
        // ================= layer-1 producer =================
        uint_t* hr = (uint_t*)&ys[0][0];   // [CH][128] packed h ring (16 KB)
        const ushort_t* xz_b = xz1h + (size_t)b * T * G4;
        float xzc[4];
#pragma unroll
        for (int gb = 0; gb < 4; ++gb) xzc[gb] = f16f(xz_b[gb * 256 + hcol]);
        __syncthreads();

        for (int t = 0; t < T; ++t) {
            const int cur = t & 1, nxt = cur ^ 1;

            f16x8 af[8];
#pragma unroll
            for (int kt = 0; kt < 8; ++kt)
                af[kt] = *(const f16x8*)((const char*)&h16[cur][0] + kt * 64 + lg * 16);

            float xzn[4];
            {
                const ushort_t* xztn = xz_b + (size_t)((t + 1 < T) ? (t + 1) : t) * G4;
#pragma unroll
                for (int gb = 0; gb < 4; ++gb) xzn[gb] = f16f(xztn[gb * 256 + hcol]);
            }

            float zg[4];
            STEP_BODY(af, xzc, zg);

            c = sig_(zg[1]) * c + sig_(zg[0]) * tanh_(zg[2]);
            float h = sig_(zg[3]) * tanh_(c);

            h16[nxt][hcol] = f16b(h);
            {
                uint_t hb = (uint_t)f16b(h);
                uint_t pb = (uint_t)(unsigned)__shfl_xor((int)hb, 1);
                if (!(l & 1))
                    hr[(t & (CH - 1)) * 128 + (hcol >> 1)] = hb | (pb << 16);
            }
#pragma unroll
            for (int gb = 0; gb < 4; ++gb) xzc[gb] = xzn[gb];

            __syncthreads();

            if ((t & (CH - 1)) == (CH - 1)) {
                int t0 = t - (CH - 1);
#pragma unroll
                for (int it = 0; it < 16; ++it) {
                    int idx = it * 256 + tid;
                    int row = idx >> 7;
                    int j = idx & 127;
                    __hip_atomic_store(&y1pk[(size_t)(b * T + t0 + row) * 128 + j],
                                       hr[row * 128 + j],
                                       __ATOMIC_RELAXED, __HIP_MEMORY_SCOPE_AGENT);
                }
                __syncthreads();
                if (tid == 0)
                    __hip_atomic_store(f1p, (t + 1) / CH, __ATOMIC_RELEASE,
                                       __HIP_MEMORY_SCOPE_AGENT);
            }
        }
    } else {
        // ================= layer-2 pure stepper =================
        size_t obase = (size_t)b * T * HID + hcol;
        __syncthreads();

        for (int ch = 0; ch < NCH; ++ch) {
            if (tid == 0) {
                while (__hip_atomic_load(f2p, __ATOMIC_ACQUIRE, __HIP_MEMORY_SCOPE_AGENT) < ch + 1)
                    __builtin_amdgcn_s_sleep(32);
            }
            __syncthreads();

            const uint_t* xzbuf = xz2u + ((size_t)(b * 4 + (ch & 3)) * CH) * G4;

            for (int tb = 0; tb < CH; ++tb) {
                const int t = ch * CH + tb;
                const int cur = t & 1, nxt = cur ^ 1;

                float xzc[4];
#pragma unroll
                for (int gb = 0; gb < 4; ++gb) {
                    uint_t u = __hip_atomic_load(&xzbuf[(size_t)tb * G4 + gb * 256 + hcol],
                                                 __ATOMIC_RELAXED, __HIP_MEMORY_SCOPE_AGENT);
                    xzc[gb] = __builtin_bit_cast(float, u);
                }

                f16x8 af[8];
#pragma unroll
                for (int kt = 0; kt < 8; ++kt)
                    af[kt] = *(const f16x8*)((const char*)&h16[cur][0] + kt * 64 + lg * 16);

                float zg[4];
                STEP_BODY(af, xzc, zg);

                c = sig_(zg[1]) * c + sig_(zg[0]) * tanh_(zg[2]);
                float h = sig_(zg[3]) * tanh_(c);

                h16[nxt][hcol] = f16b(h);
                out[obase] = h;
                obase += HID;

                __syncthreads();
            }
            if (tid == 0)
                __hip_atomic_store(f3p, ch + 1, __ATOMIC_RELEASE, __HIP_MEMORY_SCOPE_AGENT);
        }
    }
#undef STEP_BODY
}

// ---------------- launch ----------------

extern "C" void kernel_launch(void* const* d_in, const int* in_sizes, int n_in,
                              void* d_out, int out_size, void* d_ws, size_t ws_size,
                              hipStream_t stream) {
    const float* x  = (const float*)d_in[0];
    const float* W0 = (const float*)d_in[1];
    const float* U0 = (const float*)d_in[2];
    const float* b0 = (const float*)d_in[3];
    const float* W1 = (const float*)d_in[4];
    const float* U1 = (const float*)d_in[5];
    const float* b1 = (const float*)d_in[6];
    float* out = (float*)d_out;

    const size_t M = (size_t)BATCH * SEQT;   // 32768

    char* ws = (char*)d_ws;
    ushort_t* xf16  = (ushort_t*)(ws);                         // 16 MB @ 0
    uint_t*   y1pk  = (uint_t*)  (ws + (16u << 20));           // 16 MB @ 16M
    ushort_t* Wt0   = (ushort_t*)(ws + (32u << 20));           // 0.5 MB @ 32M
    ushort_t* Wt1   = (ushort_t*)(ws + (32u << 20) + 524288);  // 0.5 MB @ 32.5M
    u32x4*    Upk0  = (u32x4*)   (ws + (33u << 20));           // 0.5 MB @ 33M
    u32x4*    Upk1  = (u32x4*)   (ws + (33u << 20) + 524288);  // 0.5 MB @ 33.5M
    int*      flag1 = (int*)     (ws + (34u << 20));           // 8 KB @ 34M
    int*      flag2 = (int*)     (ws + (34u << 20) + 65536);   // 8 KB
    int*      flag3 = (int*)     (ws + (34u << 20) + 131072);  // 8 KB
    uint_t*   xz2u  = (uint_t*)  (ws + (35u << 20));           // 32 MB @ 35M (B x 4 x CH x 1024)
    ushort_t* xz1h  = (ushort_t*)(ws + (67u << 20));           // 64 MB @ 67M

    // reset handoff flags every launch (graph-replay safe)
    hipMemsetAsync(flag1, 0, 196608, stream);

    {
        int n4 = (int)(M * DIN / 4);
        cvt_x_kernel<<<dim3((n4 + 255) / 256), dim3(256), 0, stream>>>(x, xf16, n4);
        prep_wt_kernel<<<dim3(1024), dim3(256), 0, stream>>>(W0, Wt0);
        prep_wt_kernel<<<dim3(1024), dim3(256), 0, stream>>>(W1, Wt1);
        prep_upk_kernel<<<dim3(128), dim3(256), 0, stream>>>(U0, (uint4*)Upk0);
        prep_upk_kernel<<<dim3(128), dim3(256), 0, stream>>>(U1, (uint4*)Upk1);
    }

    // layer-1 input projection (f16 output)
    gemm_f16_kernel<<<dim3((int)(M / 128) * 8), dim3(256), 0, stream>>>(xf16, Wt0, b0, xz1h, (int)M);

    // 3-stage pipelined recurrence: 64 producers + 64 gemm + 64 steppers
    lstm_pipe3_kernel<<<dim3(192), dim3(256), 0, stream>>>(
        xz1h, Upk0, Upk1, Wt1, b1, y1pk, flag1, flag2, flag3, xz2u, out, SEQT);
}